// Round 5
// baseline (339.531 us; speedup 1.0000x reference)
//
#include <hip/hip_runtime.h>

// ---------------- workspace layout (float offsets) ----------------
#define AFF_OFF   0u         // [2][1024 p][1024 q]
#define XC_OFF    2097152u   // [2][1024 p][1024 q]
#define K8_OFF    4194304u   // Ktab8 [81 cls][125 item][8] (pad cols 5..7 = 0)
#define BIAS_OFF  4275328u   // [32 l][3 cd][3 ch][3 cw]
#define PART_OFF  4276224u   // topq partials [2][32][3][1024]
#define INV_OFF   4472832u   // inv norms [2 which][2 b][1024]
#define ZP_OFF    4476928u   // zero page (1024 floats)
// total 4477952 floats = 17.9 MB

#define SLOT 2184            // ring-slot stride (floats); 6 slots = 52.4 KB
#define SLOTB 8736           // byte stride

static __device__ __forceinline__ int imax(int a, int b){ return a > b ? a : b; }
static __device__ __forceinline__ int imin(int a, int b){ return a < b ? a : b; }

static __device__ __forceinline__ void ins3(float& a0, float& a1, float& a2, float v){
  if (v > a0){ a2 = a1; a1 = a0; a0 = v; }
  else if (v > a1){ a2 = a1; a1 = v; }
  else if (v > a2){ a2 = v; }
}

static __device__ __forceinline__ void fma40(const float4 fa, const float4 fb, const float4 fc,
                                             const float4 kq, const float k4, float* acc){
  acc[0] = fmaf(kq.x, fa.x, acc[0]); acc[0] = fmaf(kq.y, fa.y, acc[0]);
  acc[0] = fmaf(kq.z, fa.z, acc[0]); acc[0] = fmaf(kq.w, fa.w, acc[0]);
  acc[0] = fmaf(k4,  fb.x, acc[0]);
  acc[1] = fmaf(kq.x, fa.y, acc[1]); acc[1] = fmaf(kq.y, fa.z, acc[1]);
  acc[1] = fmaf(kq.z, fa.w, acc[1]); acc[1] = fmaf(kq.w, fb.x, acc[1]);
  acc[1] = fmaf(k4,  fb.y, acc[1]);
  acc[2] = fmaf(kq.x, fa.z, acc[2]); acc[2] = fmaf(kq.y, fa.w, acc[2]);
  acc[2] = fmaf(kq.z, fb.x, acc[2]); acc[2] = fmaf(kq.w, fb.y, acc[2]);
  acc[2] = fmaf(k4,  fb.z, acc[2]);
  acc[3] = fmaf(kq.x, fa.w, acc[3]); acc[3] = fmaf(kq.y, fb.x, acc[3]);
  acc[3] = fmaf(kq.z, fb.y, acc[3]); acc[3] = fmaf(kq.w, fb.z, acc[3]);
  acc[3] = fmaf(k4,  fb.w, acc[3]);
  acc[4] = fmaf(kq.x, fb.x, acc[4]); acc[4] = fmaf(kq.y, fb.y, acc[4]);
  acc[4] = fmaf(kq.z, fb.z, acc[4]); acc[4] = fmaf(kq.w, fb.w, acc[4]);
  acc[4] = fmaf(k4,  fc.x, acc[4]);
  acc[5] = fmaf(kq.x, fb.y, acc[5]); acc[5] = fmaf(kq.y, fb.z, acc[5]);
  acc[5] = fmaf(kq.z, fb.w, acc[5]); acc[5] = fmaf(kq.w, fc.x, acc[5]);
  acc[5] = fmaf(k4,  fc.y, acc[5]);
  acc[6] = fmaf(kq.x, fb.z, acc[6]); acc[6] = fmaf(kq.y, fb.w, acc[6]);
  acc[6] = fmaf(kq.z, fc.x, acc[6]); acc[6] = fmaf(kq.w, fc.y, acc[6]);
  acc[6] = fmaf(k4,  fc.z, acc[6]);
  acc[7] = fmaf(kq.x, fb.w, acc[7]); acc[7] = fmaf(kq.y, fc.x, acc[7]);
  acc[7] = fmaf(kq.z, fc.y, acc[7]); acc[7] = fmaf(kq.w, fc.z, acc[7]);
  acc[7] = fmaf(k4,  fc.w, acc[7]);
}

#define GLL4(gsrc, ldst) __builtin_amdgcn_global_load_lds( \
    (const __attribute__((address_space(1))) void*)(gsrc), \
    (__attribute__((address_space(3))) void*)(ldst), 4, 0, 0)

// ---------------- norms only: inv[which][b][p] = 1/max(||x[:,p]||,1e-12) ----------------
__global__ __launch_bounds__(256) void norm_k(const float* __restrict__ xp,
                                              const float* __restrict__ xq,
                                              float* __restrict__ ws){
  int bid = blockIdx.x;                 // 256: which(2) x b(2) x pg(64)
  int pg = bid & 63, b = (bid >> 6) & 1, which = bid >> 7;
  const float* src = (which ? xq : xp) + (size_t)b * 262144;
  int t = threadIdx.x, col = t & 15, cg = t >> 4;
  int p = pg * 16 + col;
  float s = 0.f;
  #pragma unroll
  for (int i = 0; i < 16; ++i){
    float v = src[(size_t)(cg * 16 + i) * 1024 + p];
    s = fmaf(v, v, s);
  }
  __shared__ float red[16][17];
  red[cg][col] = s;
  __syncthreads();
  if (t < 16){
    float tot = 0.f;
    #pragma unroll
    for (int g = 0; g < 16; ++g) tot += red[g][t];
    ws[INV_OFF + (size_t)(which * 2 + b) * 1024 + pg * 16 + t] =
        1.0f / fmaxf(sqrtf(tot), 1e-12f);
  }
}

// ---------------- precompute composed class kernels (padded), bias, zero page ----------------
__global__ __launch_bounds__(256) void tab_k(const float* __restrict__ W1,
                                             const float* __restrict__ B1,
                                             const float* __restrict__ W2,
                                             const float* __restrict__ B2,
                                             float* __restrict__ ws){
  __shared__ float sW1[1296], sW2[1296];
  for (int i = threadIdx.x; i < 1296; i += 256){ sW1[i] = W1[i]; sW2[i] = W2[i]; }
  __syncthreads();
  int tid = blockIdx.x * 256 + threadIdx.x;
  if (tid < 50625){
    int c = tid / 625, r = tid % 625;
    int cw = c % 3, ch = (c / 3) % 3, cd = (c / 9) % 3, cl = c / 27;
    int rw = r % 5, rh = (r / 5) % 5, rd = (r / 25) % 5, rl = r / 125;
    int al0 = imax(0, rl - 2), al1 = imin(2, rl);
    if (cl == 0) al0 = imax(al0, 1);
    if (cl == 2) al1 = imin(al1, 1);
    int ad0 = imax(0, rd - 2), ad1 = imin(2, rd);
    if (cd == 0) ad0 = imax(ad0, 1);
    if (cd == 2) ad1 = imin(ad1, 1);
    int ah0 = imax(0, rh - 2), ah1 = imin(2, rh);
    if (ch == 0) ah0 = imax(ah0, 1);
    if (ch == 2) ah1 = imin(ah1, 1);
    int aw0 = imax(0, rw - 2), aw1 = imin(2, rw);
    if (cw == 0) aw0 = imax(aw0, 1);
    if (cw == 2) aw1 = imin(aw1, 1);
    float s = 0.f;
    for (int a = al0; a <= al1; ++a)
      for (int bq = ad0; bq <= ad1; ++bq)
        for (int cq = ah0; cq <= ah1; ++cq)
          for (int dq = aw0; dq <= aw1; ++dq){
            int q2 = ((a * 3 + bq) * 3 + cq) * 3 + dq;
            int q1 = (((rl - a) * 3 + (rd - bq)) * 3 + (rh - cq)) * 3 + (rw - dq);
            for (int co = 0; co < 16; ++co)
              s += sW2[co * 81 + q2] * sW1[co * 81 + q1];
          }
    int item = (r * 205) >> 10;           // r/5
    int j = r - item * 5;
    ws[K8_OFF + (size_t)c * 1000 + item * 8 + j] = s;
  } else if (tid < 51489){
    int t2 = tid - 50625;
    int l = t2 / 27, rest = t2 % 27;
    int cd = rest / 9, ch = (rest / 3) % 3, cw = rest % 3;
    float v = 0.f;
    for (int i = 0; i < 3; ++i){ int y = l + i - 1; if (y >= 0 && y < 32) v += B2[i]; }
    int jlo = (cd == 0) ? 1 : 0, jhi = (cd == 2) ? 1 : 2;
    int klo = (ch == 0) ? 1 : 0, khi = (ch == 2) ? 1 : 2;
    int mlo = (cw == 0) ? 1 : 0, mhi = (cw == 2) ? 1 : 2;
    for (int i = 0; i < 3; ++i){
      int y = l + i - 1; if (y < 0 || y >= 32) continue;
      for (int co = 0; co < 16; ++co){
        float b1e = 0.f;
        for (int i2 = 0; i2 < 3; ++i2){
          int y2 = y + i2 - 1; if (y2 >= 0 && y2 < 32) b1e += B1[i2 * 16 + co];
        }
        float S = 0.f;
        for (int j = jlo; j <= jhi; ++j)
          for (int k = klo; k <= khi; ++k)
            for (int m = mlo; m <= mhi; ++m)
              S += sW2[co * 81 + ((i * 3 + j) * 3 + k) * 3 + m];
        v += b1e * S;
      }
    }
    ws[BIAS_OFF + t2] = v;
  } else if (tid < 52513){
    ws[ZP_OFF + (tid - 51489)] = 0.f;                 // zero page
  } else if (tid < 82888){
    int u = tid - 52513;                              // pad cols 5..7 of Ktab8
    int c = u / 375, r2 = u % 375;
    int item = r2 / 3, j = 5 + r2 % 3;
    ws[K8_OFF + (size_t)c * 1000 + item * 8 + j] = 0.f;
  }
}

// ---------------- aff = (xp^T xq) scaled by inv norms; 64x64 tiles, double-buffered ----------------
__global__ __launch_bounds__(256) void gemm_k(const float* __restrict__ xp,
                                              const float* __restrict__ xq,
                                              float* __restrict__ ws){
  int bid0 = blockIdx.x;
  int bid = (bid0 & 7) * 64 + (bid0 >> 3);    // XCD swizzle (512 % 8 == 0)
  int qi = bid & 15, pi = (bid >> 4) & 15, b = bid >> 8;
  const float* A = xp + (size_t)b * 262144;   // [c][p]
  const float* B = xq + (size_t)b * 262144;   // [c][q]
  float* C = ws + AFF_OFF + (size_t)b * 1048576;
  const float* invp = ws + INV_OFF + (size_t)b * 1024;
  const float* invq = ws + INV_OFF + 2048u + (size_t)b * 1024;
  int t = threadIdx.x, tx = t & 15, ty = t >> 4;
  int row = t >> 4, col = (t & 15) * 4;
  __shared__ float As[2][16][64], Bs[2][16][64];
  const float* Ag = A + (size_t)row * 1024 + pi * 64 + col;
  const float* Bg = B + (size_t)row * 1024 + qi * 64 + col;
  float4 ra = *(const float4*)Ag;
  float4 rb = *(const float4*)Bg;
  *(float4*)&As[0][row][col] = ra;
  *(float4*)&Bs[0][row][col] = rb;
  __syncthreads();
  float acc[4][4] = {};
  int cur = 0;
  for (int k0 = 16; k0 <= 256; k0 += 16){
    if (k0 < 256){
      ra = *(const float4*)(Ag + (size_t)k0 * 1024);
      rb = *(const float4*)(Bg + (size_t)k0 * 1024);
    }
    #pragma unroll
    for (int kk = 0; kk < 16; ++kk){
      float4 av = *(const float4*)&As[cur][kk][ty * 4];
      float4 bv = *(const float4*)&Bs[cur][kk][tx * 4];
      float a4[4] = {av.x, av.y, av.z, av.w};
      float b4[4] = {bv.x, bv.y, bv.z, bv.w};
      #pragma unroll
      for (int i = 0; i < 4; ++i)
        #pragma unroll
        for (int j = 0; j < 4; ++j)
          acc[i][j] = fmaf(a4[i], b4[j], acc[i][j]);
    }
    if (k0 < 256){
      int nxt = cur ^ 1;
      *(float4*)&As[nxt][row][col] = ra;
      *(float4*)&Bs[nxt][row][col] = rb;
      __syncthreads();
      cur = nxt;
    }
  }
  float4 ivb = *(const float4*)&invq[qi * 64 + tx * 4];
  #pragma unroll
  for (int i = 0; i < 4; ++i){
    float iva = invp[pi * 64 + ty * 4 + i];
    float4 v = make_float4(acc[i][0] * iva * ivb.x, acc[i][1] * iva * ivb.y,
                           acc[i][2] * iva * ivb.z, acc[i][3] * iva * ivb.w);
    *(float4*)&C[(size_t)(pi * 64 + ty * 4 + i) * 1024 + qi * 64 + tx * 4] = v;
  }
}

// ---------------- composed 5^4 conv, d-streamed, kv-in-registers, 6-slot ring ----------------
__global__ __launch_bounds__(256, 3) void conv_k(float* __restrict__ ws){
  __shared__ __align__(16) float slots[6 * SLOT];   // 52416 B -> 3 blocks/CU

  int bid0 = blockIdx.x;
  int bid = (bid0 & 7) * 128 + (bid0 >> 3);       // XCD swizzle (1024 % 8 == 0)
  int dq = bid & 3, hq = (bid >> 2) & 3, l0 = (bid >> 4) & 31, b = bid >> 9;
  int h0 = hq * 8, dstart = dq * 8;
  int t = threadIdx.x;
  const float* affB = ws + AFF_OFF + (size_t)b * 1048576;
  float* xc = ws + XC_OFF + (size_t)b * 1048576;
  const float* K8G = ws + K8_OFF;
  const float* bias = ws + BIAS_OFF;
  const float* zp = ws + ZP_OFF;

  int cl = (l0 == 0) ? 0 : (l0 == 31) ? 2 : 1;

  // A-phase lane constants: t = wv(2b) | sl(3b) | hsel(1b) | oct(2b)
  int wv = t >> 6, u3 = t & 7;
  int oct = u3 & 3, hsel = u3 >> 2, hl = wv * 2 + hsel;
  int hA = h0 + hl;
  int chA = (hA == 0) ? 0 : (hA == 31) ? 2 : 1;
  int sl = (t >> 3) & 7;

  // B-phase lane constants
  int outB = t >> 4, subB = t & 15;
  int hlB = outB >> 1, wx31 = outB & 1;
  int hB = h0 + hlB;
  int chB2 = (hB == 0) ? 0 : (hB == 31) ? 2 : 1;
  int cwB = wx31 ? 2 : 0;
  int wofB = wx31 ? 28 : 0;

  // staging global offsets (9 rounds x 256 lanes = 2160 floats/plane)
  int o0, o1, o2, o3, o4, o5, o6, o7, o8;
#define PRE(r) { int flat = (r)*256 + t; \
    int wi = flat % 36; int rest = flat / 36; int hi = rest % 12; int dl2 = rest / 12; \
    int lp_ = l0 + dl2 - 2, hp_ = h0 + hi - 2, wp_ = wi - 2; \
    bool ok = ((unsigned)lp_ < 32u) && ((unsigned)hp_ < 32u) && ((unsigned)wp_ < 32u); \
    o##r = ok ? (lp_ * 32768 + hp_ * 32 + wp_) : -1; }
  PRE(0) PRE(1) PRE(2) PRE(3) PRE(4) PRE(5) PRE(6) PRE(7) PRE(8)
#undef PRE

#define STG(r, sp_) { const float* s_ = (pOK_ && o##r >= 0) ? (affB + o##r + dpo_) : zp; \
    GLL4(s_, sp_ + (r)*256 + t); }
#define STAGE(si_, dpv_) do { \
    int dp_ = (dpv_); bool pOK_ = ((unsigned)dp_ < 32u); int dpo_ = dp_ * 1024; \
    float* sp_ = slots + (si_) * SLOT; \
    STG(0, sp_) STG(1, sp_) STG(2, sp_) STG(3, sp_) \
    STG(4, sp_) STG(5, sp_) STG(6, sp_) STG(7, sp_) \
    if (t < 112) sp_[2048 + t] = (pOK_ && o8 >= 0) ? affB[o8 + dpo_] : 0.f; \
  } while (0)

  // per-lane item table + kv registers (invariant across steps until cd changes)
  int pk_[16];            // ((dl*12+hl+dh)*36 + oct*8)*4 | dd
  float4 kvq_[16];
  float kv4_[16];
  int cdCur = (dstart == 0) ? 0 : 1;
  const float* kvGb = K8G + (size_t)((((cl * 3 + cdCur) * 3 + chA) * 3) + 1) * 1000;
  #pragma unroll
  for (int k = 0; k < 16; ++k){
    int e = sl + 8 * k;
    int ec = imin(e, 124);
    int dl = (ec * 41) >> 10;  int rem = ec - dl * 25;
    int dd = (rem * 205) >> 10; int dh = rem - dd * 5;
    pk_[k] = ((((dl * 12 + hl + dh) * 36 + oct * 8) << 2)) | dd;
    kvq_[k] = *(const float4*)(kvGb + ec * 8);
    kv4_[k] = kvGb[ec * 8 + 4];
  }

  // prologue: stage planes dstart-2 .. dstart+2 into ring slots (P+12)%6
  STAGE((dstart + 10) % 6, dstart - 2);
  STAGE((dstart + 11) % 6, dstart - 1);
  STAGE((dstart + 12) % 6, dstart);
  STAGE((dstart + 13) % 6, dstart + 1);
  STAGE((dstart + 14) % 6, dstart + 2);
  asm volatile("s_waitcnt vmcnt(0)" ::: "memory");
  __syncthreads();

  for (int s8 = 0; s8 < 8; ++s8){
    int d = dstart + s8;
    int cd = (d == 0) ? 0 : (d == 31) ? 2 : 1;
    if (cd != cdCur){                               // block-uniform, rare
      cdCur = cd;
      kvGb = K8G + (size_t)((((cl * 3 + cd) * 3 + chA) * 3) + 1) * 1000;
      #pragma unroll
      for (int k = 0; k < 16; ++k){
        int ec = imin(sl + 8 * k, 124);
        kvq_[k] = *(const float4*)(kvGb + ec * 8);
        kv4_[k] = kvGb[ec * 8 + 4];
      }
    }
    int sbase6 = (d + 10) % 6;                      // ring slot of plane d-2

    if (s8 < 7) STAGE((d + 15) % 6, d + 3);         // async prefetch plane d+3

    // ---- A-phase: 125 items, kv from regs, 3 ds_read_b128 + 40 FMA each ----
    float acc[8] = {0.f, 0.f, 0.f, 0.f, 0.f, 0.f, 0.f, 0.f};
    #pragma unroll
    for (int k = 0; k < 16; ++k){
      if (k < 15 || sl < 5){
        int dd = pk_[k] & 7;
        int rowb = pk_[k] & ~7;
        int s6 = sbase6 + dd; s6 -= (s6 >= 6) ? 6 : 0;
        const float* rp = (const float*)((const char*)slots + s6 * SLOTB + rowb);
        float4 fa = *(const float4*)rp;
        float4 fb = *(const float4*)(rp + 4);
        float4 fc = *(const float4*)(rp + 8);
        fma40(fa, fb, fc, kvq_[k], kv4_[k], acc);
      }
    }

    // ---- B-phase: w in {0,31} columns, kv from global (L1-hot) ----
    float accB = 0.f;
    {
      const float* kgB = K8G + (size_t)((((cl * 3 + cd) * 3 + chB2) * 3) + cwB) * 1000;
      for (int e = subB; e < 125; e += 16){
        int dlb = (e * 41) >> 10;  int remb = e - dlb * 25;
        int ddb = (remb * 205) >> 10; int rhb = remb - ddb * 5;
        int s6 = sbase6 + ddb; s6 -= (s6 >= 6) ? 6 : 0;
        const float* rp = slots + s6 * SLOT + (dlb * 12 + hlB + rhb) * 36 + wofB;
        float4 q1 = *(const float4*)rp;
        float4 q2 = *(const float4*)(rp + 4);
        const float* ka = kgB + e * 8;
        float4 kq = *(const float4*)ka;
        float k4 = ka[4];
        float e0 = wx31 ? q1.w : q1.x;
        float e1 = wx31 ? q2.x : q1.y;
        float e2 = wx31 ? q2.y : q1.z;
        float e3 = wx31 ? q2.z : q1.w;
        float e4 = wx31 ? q2.w : q2.x;
        accB = fmaf(kq.x, e0, accB); accB = fmaf(kq.y, e1, accB);
        accB = fmaf(kq.z, e2, accB); accB = fmaf(kq.w, e3, accB);
        accB = fmaf(k4,  e4, accB);
      }
    }

    // ---- A reduce-scatter butterfly over sl bits (7 shfl) ----
    {
      bool b1 = (sl & 1) != 0;
      float s0 = b1 ? acc[0] : acc[4];
      float s1 = b1 ? acc[1] : acc[5];
      float s2 = b1 ? acc[2] : acc[6];
      float s3 = b1 ? acc[3] : acc[7];
      s0 = __shfl_xor(s0, 8); s1 = __shfl_xor(s1, 8);
      s2 = __shfl_xor(s2, 8); s3 = __shfl_xor(s3, 8);
      float c0 = (b1 ? acc[4] : acc[0]) + s0;
      float c1 = (b1 ? acc[5] : acc[1]) + s1;
      float c2 = (b1 ? acc[6] : acc[2]) + s2;
      float c3 = (b1 ? acc[7] : acc[3]) + s3;
      bool b2 = (sl & 2) != 0;
      float u0 = b2 ? c0 : c2;
      float u1 = b2 ? c1 : c3;
      u0 = __shfl_xor(u0, 16); u1 = __shfl_xor(u1, 16);
      float m0 = (b2 ? c2 : c0) + u0;
      float m1 = (b2 ? c3 : c1) + u1;
      bool b3 = (sl & 4) != 0;
      float v0 = b3 ? m0 : m1;
      v0 = __shfl_xor(v0, 32);
      float r = (b3 ? m1 : m0) + v0;
      int wA = oct * 8 + ((sl & 1) << 2) + (sl & 2) + ((sl >> 2) & 1);
      if (wA != 0 && wA != 31){
        float bvA = bias[l0 * 27 + cd * 9 + chA * 3 + 1];
        xc[(size_t)(l0 * 32 + d) * 1024 + hA * 32 + wA] = r + bvA;
      }
    }

    // ---- B reduction (16 sub-lanes) + store ----
    accB += __shfl_xor(accB, 1);
    accB += __shfl_xor(accB, 2);
    accB += __shfl_xor(accB, 4);
    accB += __shfl_xor(accB, 8);
    if (subB == 0){
      float bvB = bias[l0 * 27 + cd * 9 + chB2 * 3 + cwB];
      xc[(size_t)(l0 * 32 + d) * 1024 + hB * 32 + (wx31 ? 31 : 0)] = accB + bvB;
    }

    asm volatile("s_waitcnt vmcnt(0)" ::: "memory");   // staged plane landed
    __syncthreads();
  }
#undef STG
#undef STAGE
}

// ---------------- valp: top3 over q for each (b,p); wave per row, float4 ----------------
__global__ __launch_bounds__(256) void topp_k(const float* __restrict__ ws, float* __restrict__ out){
  const float* xc = ws + XC_OFF;
  int wid = blockIdx.x * 4 + (threadIdx.x >> 6);
  int lane = threadIdx.x & 63;
  int b = wid >> 10, p = wid & 1023;
  const float4* row4 = (const float4*)(xc + (size_t)b * 1048576 + (size_t)p * 1024);
  float a0 = -3.4e38f, a1 = a0, a2 = a0;
  #pragma unroll
  for (int j = 0; j < 4; ++j){
    float4 v = row4[j * 64 + lane];
    ins3(a0, a1, a2, v.x); ins3(a0, a1, a2, v.y);
    ins3(a0, a1, a2, v.z); ins3(a0, a1, a2, v.w);
  }
  for (int off = 32; off; off >>= 1){
    float b0 = __shfl_xor(a0, off), b1 = __shfl_xor(a1, off), b2 = __shfl_xor(a2, off);
    ins3(a0, a1, a2, b0); ins3(a0, a1, a2, b1); ins3(a0, a1, a2, b2);
  }
  if (lane < 3){
    float v = (lane == 0) ? a0 : (lane == 1) ? a1 : a2;
    out[b * 3072 + lane * 1024 + p] = v;
  }
}

// ---------------- valq: top3 over p for each (b,q); 2-stage coalesced ----------------
__global__ __launch_bounds__(256) void topq1_k(float* __restrict__ ws){
  const float* xc = ws + XC_OFF;
  float* part = ws + PART_OFF;
  int bid = blockIdx.x;                       // 256: b(2) x pc(32) x qq(4)
  int qq = bid & 3, pc = (bid >> 2) & 31, b = bid >> 7;
  int q = qq * 256 + threadIdx.x;
  const float* base = xc + (size_t)b * 1048576 + q;
  float a0 = -3.4e38f, a1 = a0, a2 = a0;
  #pragma unroll 4
  for (int i = 0; i < 32; ++i) ins3(a0, a1, a2, base[(size_t)(pc * 32 + i) * 1024]);
  part[(size_t)((b * 32 + pc) * 3 + 0) * 1024 + q] = a0;
  part[(size_t)((b * 32 + pc) * 3 + 1) * 1024 + q] = a1;
  part[(size_t)((b * 32 + pc) * 3 + 2) * 1024 + q] = a2;
}

__global__ __launch_bounds__(256) void topq2_k(const float* __restrict__ ws, float* __restrict__ out){
  const float* part = ws + PART_OFF;
  int gid = blockIdx.x * 256 + threadIdx.x;   // 2048
  int b = gid >> 10, q = gid & 1023;
  float a0 = -3.4e38f, a1 = a0, a2 = a0;
  #pragma unroll 4
  for (int c = 0; c < 96; ++c) ins3(a0, a1, a2, part[(size_t)(b * 96 + c) * 1024 + q]);
  out[6144 + b * 3072 + q] = a0;
  out[6144 + b * 3072 + 1024 + q] = a1;
  out[6144 + b * 3072 + 2048 + q] = a2;
}

extern "C" void kernel_launch(void* const* d_in, const int* in_sizes, int n_in,
                              void* d_out, int out_size, void* d_ws, size_t ws_size,
                              hipStream_t stream){
  const float* xp = (const float*)d_in[0];
  const float* xq = (const float*)d_in[1];
  const float* W1 = (const float*)d_in[2];
  const float* B1 = (const float*)d_in[3];
  const float* W2 = (const float*)d_in[4];
  const float* B2 = (const float*)d_in[5];
  float* out = (float*)d_out;
  float* ws = (float*)d_ws;
  hipLaunchKernelGGL(norm_k,  dim3(256),  dim3(256), 0, stream, xp, xq, ws);
  hipLaunchKernelGGL(tab_k,   dim3(324),  dim3(256), 0, stream, W1, B1, W2, B2, ws);
  hipLaunchKernelGGL(gemm_k,  dim3(512),  dim3(256), 0, stream, xp, xq, ws);
  hipLaunchKernelGGL(conv_k,  dim3(1024), dim3(256), 0, stream, ws);
  hipLaunchKernelGGL(topp_k,  dim3(512),  dim3(256), 0, stream, ws, out);
  hipLaunchKernelGGL(topq1_k, dim3(256),  dim3(256), 0, stream, ws);
  hipLaunchKernelGGL(topq2_k, dim3(8),    dim3(256), 0, stream, ws, out);
}